// Round 1
// baseline (340.338 us; speedup 1.0000x reference)
//
#include <hip/hip_runtime.h>
#include <cstdint>

constexpr int B = 32, C = 256, H = 56, W = 56;
constexpr int HW = H * W;          // 3136
constexpr int WORDS = C / 32;      // 8 u32 words per pixel
constexpr int TAPS = 9;
constexpr int WPC = TAPS * WORDS;  // 72 words of weights per output channel

// ---------------------------------------------------------------------------
// Pack x signs: px[b][hw][word] ; bit i of word wd = (x[b][wd*32+i][h][w] < 0)
// Coalesced: for fixed channel c, consecutive threads (consecutive hw) read
// consecutive addresses.
// ---------------------------------------------------------------------------
__global__ __launch_bounds__(256) void pack_x_kernel(const float* __restrict__ x,
                                                     uint32_t* __restrict__ px) {
    int idx = blockIdx.x * 256 + threadIdx.x;
    if (idx >= B * HW) return;
    int b = idx / HW;
    int hw = idx - b * HW;
    const float* xp = x + (size_t)b * C * HW + hw;
    uint32_t words[WORDS];
    for (int wd = 0; wd < WORDS; ++wd) {
        uint32_t bits = 0;
        #pragma unroll
        for (int i = 0; i < 32; ++i) {
            bits |= (xp[(size_t)(wd * 32 + i) * HW] < 0.0f ? (1u << i) : 0u);
        }
        words[wd] = bits;
    }
    uint4* dst = reinterpret_cast<uint4*>(px + (size_t)idx * WORDS);
    dst[0] = make_uint4(words[0], words[1], words[2], words[3]);
    dst[1] = make_uint4(words[4], words[5], words[6], words[7]);
}

// ---------------------------------------------------------------------------
// Pack w signs: pw[co][tap][word], tap = kh*3+kw.
// weight layout is [co][ci][kh][kw]; element (co, ci=wd*32+i, tap) is at
// (co*C + ci)*9 + tap.
// ---------------------------------------------------------------------------
__global__ __launch_bounds__(256) void pack_w_kernel(const float* __restrict__ wt,
                                                     uint32_t* __restrict__ pw) {
    int idx = blockIdx.x * 256 + threadIdx.x;
    if (idx >= C * WPC) return;
    int co = idx / WPC;
    int r = idx - co * WPC;
    int tap = r / WORDS;
    int wd = r - tap * WORDS;
    const float* wp = wt + ((size_t)co * C + wd * 32) * TAPS + tap;
    uint32_t bits = 0;
    #pragma unroll
    for (int i = 0; i < 32; ++i)
        bits |= (wp[(size_t)i * TAPS] < 0.0f ? (1u << i) : 0u);
    pw[(size_t)co * WPC + (size_t)tap * WORDS + wd] = bits;
}

// ---------------------------------------------------------------------------
// Binary conv: one wave = 64 consecutive hw positions of one batch image,
// one block = one 64-channel co-chunk. Each lane holds its 9-tap x-bit
// neighborhood (72 u32) in registers across the whole co loop; weights are
// accessed at a wave-uniform address (blockIdx/loop only) so they can ride
// the scalar pipe.  dot = 256*n_valid - 2*sum(popc(xor)) over valid taps.
// ---------------------------------------------------------------------------
__global__ __launch_bounds__(64) void bconv_kernel(const uint32_t* __restrict__ px,
                                                   const uint32_t* __restrict__ pw,
                                                   const float* __restrict__ bias,
                                                   float* __restrict__ out) {
    const int lane = threadIdx.x;
    const int hw = blockIdx.x * 64 + lane;     // 3136 = 49 waves * 64, exact
    const int cobase = blockIdx.y * 64;
    const int b = blockIdx.z;
    const int h = hw / W;
    const int w = hw - h * W;

    uint32_t pxr[TAPS][WORDS];
    bool valid[TAPS];
    int nvalid = 0;
    #pragma unroll
    for (int dh = -1; dh <= 1; ++dh) {
        #pragma unroll
        for (int dw = -1; dw <= 1; ++dw) {
            const int t = (dh + 1) * 3 + (dw + 1);
            const int hh = h + dh, ww = w + dw;
            const bool v = (hh >= 0) & (hh < H) & (ww >= 0) & (ww < W);
            valid[t] = v;
            nvalid += v ? 1 : 0;
            if (v) {
                const uint4* p = reinterpret_cast<const uint4*>(
                    px + ((size_t)b * HW + (size_t)hh * W + ww) * WORDS);
                uint4 a = p[0], bq = p[1];
                pxr[t][0] = a.x;  pxr[t][1] = a.y;  pxr[t][2] = a.z;  pxr[t][3] = a.w;
                pxr[t][4] = bq.x; pxr[t][5] = bq.y; pxr[t][6] = bq.z; pxr[t][7] = bq.w;
            } else {
                #pragma unroll
                for (int k = 0; k < WORDS; ++k) pxr[t][k] = 0;
            }
        }
    }

    const float basef = (float)(256 * nvalid);
    float* op = out + ((size_t)b * C + cobase) * HW + hw;

    #pragma unroll 1
    for (int j = 0; j < 64; ++j) {
        const int co = cobase + j;
        const uint32_t* wrow = pw + (size_t)co * WPC;  // wave-uniform address
        uint32_t total = 0;
        #pragma unroll
        for (int t = 0; t < TAPS; ++t) {
            uint32_t pt = 0;
            #pragma unroll
            for (int k = 0; k < WORDS; ++k)
                pt += __popc(pxr[t][k] ^ wrow[t * WORDS + k]);
            total += valid[t] ? pt : 0u;
        }
        float res = basef - 2.0f * (float)(int)total + bias[co];
        op[(size_t)j * HW] = res;
    }
}

extern "C" void kernel_launch(void* const* d_in, const int* in_sizes, int n_in,
                              void* d_out, int out_size, void* d_ws, size_t ws_size,
                              hipStream_t stream) {
    const float* x = (const float*)d_in[0];
    const float* wt = (const float*)d_in[1];
    const float* bias = (const float*)d_in[2];
    float* out = (float*)d_out;

    uint32_t* px = (uint32_t*)d_ws;                    // 32*3136*8*4 = 3,211,264 B
    uint32_t* pw = px + (size_t)B * HW * WORDS;        // + 73,728 B

    pack_x_kernel<<<(B * HW + 255) / 256, 256, 0, stream>>>(x, px);
    pack_w_kernel<<<(C * WPC + 255) / 256, 256, 0, stream>>>(wt, pw);

    dim3 grid(HW / 64, C / 64, B);
    bconv_kernel<<<grid, 64, 0, stream>>>(px, pw, bias, out);
}